// Round 5
// baseline (1824.063 us; speedup 1.0000x reference)
//
#include <hip/hip_runtime.h>
#include <cstdint>

#define NBATCH 4096
#define NNODE  64
#define FEAT   32
#define H      128
#define NE     4
#define NL     3

typedef __attribute__((ext_vector_type(8))) short short8;
typedef __attribute__((ext_vector_type(4))) short short4v;
typedef __attribute__((ext_vector_type(4))) float f32x4;
typedef __attribute__((ext_vector_type(2))) float f32x2;

// ws image sizes
#define IMG_GC_ELEMS   (128 * 64)          // one (layer,edge,kh) image, shorts
#define IMG_GRU_ELEMS  (48 * 128)          // one (mat,chunk) image, shorts
#define IMG_GC_BYTES   (24 * IMG_GC_ELEMS * 2)    // 393216
#define IMG_GRU_BYTES  (16 * IMG_GRU_ELEMS * 2)   // 196608
#define WS_NEEDED      (IMG_GC_BYTES + IMG_GRU_BYTES)

__device__ __forceinline__ unsigned short f2b(float f) {
  union { float f; unsigned u; } v; v.f = f;
  unsigned u = v.u + 0x7FFFu + ((v.u >> 16) & 1u);   // RNE
  return (unsigned short)(u >> 16);
}
__device__ __forceinline__ float b2f(unsigned short s) {
  union { unsigned u; float f; } v; v.u = ((unsigned)s) << 16;
  return v.f;
}
__device__ __forceinline__ float sigm(float v) { return 1.0f / (1.0f + __expf(-v)); }
__device__ __forceinline__ float tanh_(float v) {
  v = fminf(fmaxf(v, -15.f), 15.f);
  float e = __expf(-2.f * v);
  return (1.f - e) / (1.f + e);
}
__device__ __forceinline__ int gidx128(int r, int g) { return r * 128 + ((g ^ (r & 7)) << 3); }
__device__ __forceinline__ int idx128(int r, int k) { return gidx128(r, k >> 3) + (k & 7); }
__device__ __forceinline__ int gidx64(int r, int g) { return r * 64 + (((g ^ (r & 7)) & 7) << 3); }

__device__ __forceinline__ short8 pack8(const float* v) {
  short8 r;
  #pragma unroll
  for (int j = 0; j < 8; ++j) r[j] = (short)f2b(v[j]);
  return r;
}

__device__ __forceinline__ void gll16(const void* g, void* l) {
  __builtin_amdgcn_global_load_lds(
      (const __attribute__((address_space(1))) unsigned int*)g,
      (__attribute__((address_space(3))) unsigned int*)l, 16, 0, 0);
}

// stage NIT*4 KiB image (NIT=4 -> 16KB, NIT=3 -> 12KB), all 4 waves
#define STAGE(dst, src, NIT)                                             \
  do {                                                                   \
    _Pragma("unroll")                                                    \
    for (int it_ = 0; it_ < (NIT); ++it_) {                              \
      int off_ = (it_ * 4 + w) * 1024;                                   \
      gll16((const char*)(src) + off_ + lane * 16, (char*)(dst) + off_); \
    }                                                                    \
  } while (0)

// ============ K0: build bf16 weight images in ws (exact swizzled LDS byte order) ========
__global__ __launch_bounds__(256, 2) void k_prep(
    const float* __restrict__ gc_w, const float* __restrict__ w_ih,
    const float* __restrict__ w_hh, unsigned short* __restrict__ ws)
{
  const int t = threadIdx.x;
  if (blockIdx.x < 24) {
    const int blk = blockIdx.x;
    const int kh = blk & 1, e = (blk >> 1) & 3, l = blk >> 3;
    const float* We = gc_w + (size_t)(l * NE + e) * H * H;
    unsigned short* dst = ws + (size_t)blk * IMG_GC_ELEMS;
    #pragma unroll
    for (int it = 0; it < 4; ++it) {
      int idx = t + it * 256;
      int r = idx >> 3, g = idx & 7;
      float v[8];
      #pragma unroll
      for (int j = 0; j < 8; ++j) v[j] = We[(kh * 64 + g * 8 + j) * H + r];
      *(short8*)&dst[gidx64(r, g)] = pack8(v);
    }
  } else {
    const int blk = blockIdx.x - 24;
    const int c = blk & 7, m = blk >> 3;
    const float* Mat = m ? w_hh : w_ih;
    unsigned short* dst = ws + IMG_GC_BYTES / 2 + (size_t)blk * IMG_GRU_ELEMS;
    #pragma unroll
    for (int it = 0; it < 3; ++it) {
      int idx = t + it * 256;
      int rr = idx >> 4, g = idx & 15;
      int mrow = (rr >> 4) * H + 16 * c + (rr & 15);
      float v[8];
      #pragma unroll
      for (int j = 0; j < 8; ++j) v[j] = Mat[mrow * H + g * 8 + j];
      *(short8*)&dst[gidx128(rr, g)] = pack8(v);
    }
  }
}

// ================= K1: per-node input embedding -> bf16 h0 in out-row tails =============
__global__ __launch_bounds__(256, 2) void k_inemb(
    const float* __restrict__ x, const float* __restrict__ in_w,
    const float* __restrict__ in_b, float* __restrict__ out)
{
  __shared__ float s_wt[FEAT * H];
  __shared__ float s_x[64 * FEAT];
  const int t = threadIdx.x;
  const int n = blockIdx.x >> 6, bt = blockIdx.x & 63, b0 = bt * 64;
  const float* wsrc = in_w + (size_t)n * FEAT * H;
  #pragma unroll
  for (int it = 0; it < 4; ++it) {
    int i4 = t + it * 256;
    *(f32x4*)&s_wt[i4 * 4] = *(const f32x4*)&wsrc[i4 * 4];
  }
  {
    int r = t >> 2, q = t & 3;
    const float* xs = x + ((size_t)(b0 + r) * NNODE + n) * FEAT;
    *(f32x4*)&s_x[r * 32 + q * 8]     = *(const f32x4*)&xs[q * 8];
    *(f32x4*)&s_x[r * 32 + q * 8 + 4] = *(const f32x4*)&xs[q * 8 + 4];
  }
  __syncthreads();
  const int h2 = t & 63, rp = t >> 6;
  const float bi0 = in_b[n * H + 2 * h2], bi1 = in_b[n * H + 2 * h2 + 1];
  #pragma unroll 1
  for (int m = 0; m < 16; ++m) {
    int r = rp + 4 * m;
    float a0 = bi0, a1 = bi1;
    #pragma unroll
    for (int d = 0; d < 32; ++d) {
      float xv = s_x[r * 32 + d];
      f32x2 wv = *(const f32x2*)&s_wt[d * H + 2 * h2];
      a0 += xv * wv.x; a1 += xv * wv.y;
    }
    unsigned p = (unsigned)f2b(a0) | ((unsigned)f2b(a1) << 16);
    unsigned short* tail = (unsigned short*)(out + ((size_t)(b0 + r) * NNODE + n) * H + 64);
    *(unsigned*)(tail + 2 * h2) = p;
  }
}

// ================= K2: 3 layers of RGCN + GRU, phase-pipelined MFMA =============
__global__ __launch_bounds__(256, 2) void k_main(
    const float* __restrict__ adj,
    const float* __restrict__ gc_b,
    const float* __restrict__ b_ih, const float* __restrict__ b_hh,
    const unsigned short* __restrict__ wimg,
    float* __restrict__ out)
{
  __shared__ unsigned short s_cur[64 * 128];  // hidden, in-place update
  __shared__ unsigned short s_u[128 * 64];    // S^T [h][j] / xf [i][h]
  __shared__ unsigned short s_w0[128 * 64];   // weight dbuf A
  __shared__ unsigned short s_w1[128 * 64];   // weight dbuf B
  __shared__ float s_bias[1280];              // gc_b layer slice | b_ih | b_hh

  const int t = threadIdx.x;
  const int b = blockIdx.x;
  const int w = t >> 6, lane = t & 63, lr = lane & 15, lq = lane >> 4;
  float* outb = out + (size_t)b * NNODE * H;
  const unsigned short* img_gru = wimg + IMG_GC_BYTES / 2;

  // ---- prologue: prefetch W(l0,e0,kh0); h0 from out-row tails; GRU biases ----
  STAGE(s_w0, wimg, 4);
  #pragma unroll
  for (int it = 0; it < 4; ++it) {
    int idx = t + it * 256;
    int n = idx >> 4, g = idx & 15;
    short8 v = *(const short8*)((const unsigned short*)(outb + n * H + 64) + g * 8);
    *(short8*)&s_cur[gidx128(n, g)] = v;
  }
  #pragma unroll
  for (int it = 0; it < 3; ++it) {
    int idx = t + it * 256;
    s_bias[512 + idx] = (idx < 384) ? b_ih[idx] : b_hh[idx - 384];
  }
  __syncthreads();

  #pragma unroll 1
  for (int layer = 0; layer < NL; ++layer) {
    f32x4 agg[8];
    #pragma unroll
    for (int tn = 0; tn < 8; ++tn) agg[tn] = f32x4{0.f, 0.f, 0.f, 0.f};

    // ======== edges: 3 barriers each, all stages issued a full phase early ====
    #pragma unroll 1
    for (int e = 0; e < NE; ++e) {
      const unsigned short* img_e = wimg + (size_t)((layer * NE + e) * 2) * IMG_GC_ELEMS;
      // ---- P2: issue adj reg-loads + W1<-kh1; compute mm1 kh0 from W0 ----
      f32x4 ar0, ar1, ar2, ar3;
      {
        const float* arow = adj + (((size_t)b * NE + e) * NNODE + (16 * w + lr)) * NNODE;
        ar0 = *(const f32x4*)&arow[lq * 8];
        ar1 = *(const f32x4*)&arow[lq * 8 + 4];
        ar2 = *(const f32x4*)&arow[32 + lq * 8];
        ar3 = *(const f32x4*)&arow[32 + lq * 8 + 4];
      }
      STAGE(s_w1, img_e + IMG_GC_ELEMS, 4);
      if (e == 0) {  // stage this layer's gc_b slice (first read at P4)
        s_bias[t]       = gc_b[layer * 512 + t];
        s_bias[t + 256] = gc_b[layer * 512 + t + 256];
      }
      f32x4 Sacc[8];
      #pragma unroll
      for (int tn = 0; tn < 8; ++tn) Sacc[tn] = f32x4{0.f, 0.f, 0.f, 0.f};
      #pragma unroll
      for (int ks = 0; ks < 2; ++ks) {
        short8 a = *(const short8*)&s_cur[gidx128(16 * w + lr, ks * 4 + lq)];
        #pragma unroll
        for (int tn = 0; tn < 8; ++tn) {
          short8 bb = *(const short8*)&s_w0[gidx64(16 * tn + lr, ks * 4 + lq)];
          Sacc[tn] = __builtin_amdgcn_mfma_f32_16x16x32_bf16(a, bb, Sacc[tn], 0, 0, 0);
        }
      }
      __syncthreads();   // W1 + adj regs ready (hidden under mm1 kh0)

      // ---- P3: issue W0<-next; mm1 kh1 from W1; pack S^T -> s_u ----
      if (e < 3) STAGE(s_w0, img_e + 2 * IMG_GC_ELEMS, 4);
      else       STAGE(s_w0, img_gru, 3);            // GRU ih(0)
      #pragma unroll
      for (int ks = 0; ks < 2; ++ks) {
        short8 a = *(const short8*)&s_cur[gidx128(16 * w + lr, 8 + ks * 4 + lq)];
        #pragma unroll
        for (int tn = 0; tn < 8; ++tn) {
          short8 bb = *(const short8*)&s_w1[gidx64(16 * tn + lr, ks * 4 + lq)];
          Sacc[tn] = __builtin_amdgcn_mfma_f32_16x16x32_bf16(a, bb, Sacc[tn], 0, 0, 0);
        }
      }
      {
        int nb = 16 * w + 4 * lq;
        int g = nb >> 3, sub = nb & 7;
        #pragma unroll
        for (int tn = 0; tn < 8; ++tn) {
          int h = 16 * tn + lr;
          short4v p;
          #pragma unroll
          for (int r = 0; r < 4; ++r) p[r] = (short)f2b(Sacc[tn][r]);
          *(short4v*)&s_u[gidx64(h, g) + sub] = p;
        }
      }
      __syncthreads();   // S^T visible; W0(next) ready

      // ---- P4: adj frags from regs; mm2; agg += relu ----
      {
        short8 af[2];
        {
          float v[8];
          for (int j = 0; j < 4; ++j) { v[j] = ar0[j]; v[4 + j] = ar1[j]; }
          af[0] = pack8(v);
        }
        {
          float v[8];
          for (int j = 0; j < 4; ++j) { v[j] = ar2[j]; v[4 + j] = ar3[j]; }
          af[1] = pack8(v);
        }
        f32x4 Oacc[8];
        #pragma unroll
        for (int tn = 0; tn < 8; ++tn) Oacc[tn] = f32x4{0.f, 0.f, 0.f, 0.f};
        #pragma unroll
        for (int ks = 0; ks < 2; ++ks) {
          #pragma unroll
          for (int tn = 0; tn < 8; ++tn) {
            short8 bb = *(const short8*)&s_u[gidx64(16 * tn + lr, ks * 4 + lq)];
            Oacc[tn] = __builtin_amdgcn_mfma_f32_16x16x32_bf16(af[ks], bb, Oacc[tn], 0, 0, 0);
          }
        }
        #pragma unroll
        for (int tn = 0; tn < 8; ++tn) {
          float bias = s_bias[e * 128 + 16 * tn + lr];
          #pragma unroll
          for (int r = 0; r < 4; ++r)
            agg[tn][r] += 0.25f * fmaxf(Oacc[tn][r] + bias, 0.f);
        }
      }
      __syncthreads();   // close s_u reads (rewritten next edge P3)
    }  // edges

    // ---- xf = agg -> s_u row-major [i][h] ----
    #pragma unroll
    for (int tn = 0; tn < 8; ++tn) {
      int h = 16 * tn + lr;
      #pragma unroll
      for (int r = 0; r < 4; ++r) {
        int i = 16 * w + 4 * lq + r;
        s_u[idx128(i, h)] = f2b(agg[tn][r]);
      }
    }
    __syncthreads();

    // ======== GRU: 8 chunks fully unrolled, h' in registers, 2 barriers/chunk ====
    short4v hreg[8];
    #pragma unroll
    for (int c = 0; c < 8; ++c) {
      // Pgi: issue W1<-hh(c); gi(c) from W0 + xf
      STAGE(s_w1, img_gru + (size_t)(8 + c) * IMG_GRU_ELEMS, 3);
      f32x4 gi[3], gh[3];
      #pragma unroll
      for (int tg = 0; tg < 3; ++tg) gi[tg] = f32x4{0.f, 0.f, 0.f, 0.f};
      #pragma unroll
      for (int ks = 0; ks < 4; ++ks) {
        short8 bb = *(const short8*)&s_u[gidx128(16 * w + lr, ks * 4 + lq)];
        #pragma unroll
        for (int tg = 0; tg < 3; ++tg) {
          short8 a = *(const short8*)&s_w0[gidx128(16 * tg + lr, ks * 4 + lq)];
          gi[tg] = __builtin_amdgcn_mfma_f32_16x16x32_bf16(a, bb, gi[tg], 0, 0, 0);
        }
      }
      __syncthreads();   // W1/hh(c) ready (hidden under gi)

      // Pgh: issue W0<-ih(c+1) | next-layer gc(e0,kh0); gh(c) from W1 + cur; gates
      if (c < 7)          STAGE(s_w0, img_gru + (size_t)(c + 1) * IMG_GRU_ELEMS, 3);
      else if (layer < 2) STAGE(s_w0, wimg + (size_t)((layer + 1) * NE * 2) * IMG_GC_ELEMS, 4);
      #pragma unroll
      for (int tg = 0; tg < 3; ++tg) gh[tg] = f32x4{0.f, 0.f, 0.f, 0.f};
      #pragma unroll
      for (int ks = 0; ks < 4; ++ks) {
        short8 bb = *(const short8*)&s_cur[gidx128(16 * w + lr, ks * 4 + lq)];
        #pragma unroll
        for (int tg = 0; tg < 3; ++tg) {
          short8 a = *(const short8*)&s_w1[gidx128(16 * tg + lr, ks * 4 + lq)];
          gh[tg] = __builtin_amdgcn_mfma_f32_16x16x32_bf16(a, bb, gh[tg], 0, 0, 0);
        }
      }
      {
        int i = 16 * w + lr;
        int g = (16 * c + 4 * lq) >> 3;
        int off = gidx128(i, g) + ((4 * lq) & 7);
        short4v hv = *(const short4v*)&s_cur[off];
        #pragma unroll
        for (int r = 0; r < 4; ++r) {
          int mH = 16 * c + 4 * lq + r;
          float rg = sigm(gi[0][r] + s_bias[512 + mH] + gh[0][r] + s_bias[896 + mH]);
          float zg = sigm(gi[1][r] + s_bias[640 + mH] + gh[1][r] + s_bias[1024 + mH]);
          float ng = tanh_(gi[2][r] + s_bias[768 + mH] + rg * (gh[2][r] + s_bias[1152 + mH]));
          float hold = b2f((unsigned short)hv[r]);
          hreg[c][r] = (short)f2b((1.f - zg) * ng + zg * hold);
        }
      }
      __syncthreads();   // close gh(c) cur/W1 reads
    }  // chunks

    // in-place write-back of h'
    #pragma unroll
    for (int c = 0; c < 8; ++c) {
      int off = gidx128(16 * w + lr, (16 * c + 4 * lq) >> 3) + ((4 * lq) & 7);
      *(short4v*)&s_cur[off] = hreg[c];
    }
    __syncthreads();
  }  // layers

  // write final hidden (bf16) back into out-row tails
  #pragma unroll
  for (int it = 0; it < 4; ++it) {
    int idx = t + it * 256;
    int n = idx >> 4, g = idx & 15;
    short8 v = *(const short8*)&s_cur[gidx128(n, g)];
    *(short8*)((unsigned short*)(outb + n * H + 64) + g * 8) = v;
  }
}

// ================= K3: per-node output embedding + zero pad =============
__global__ __launch_bounds__(256, 2) void k_outemb(
    const float* __restrict__ out_w, const float* __restrict__ out_b,
    float* __restrict__ out)
{
  __shared__ float s_wt[H * FEAT];
  __shared__ float s_c[64 * 132];
  const int t = threadIdx.x;
  const int n = blockIdx.x >> 6, bt = blockIdx.x & 63, b0 = bt * 64;
  const float* wsrc = out_w + (size_t)n * H * FEAT;
  #pragma unroll
  for (int it = 0; it < 4; ++it) {
    int i4 = t + it * 256;
    *(f32x4*)&s_wt[i4 * 4] = *(const f32x4*)&wsrc[i4 * 4];
  }
  #pragma unroll
  for (int it = 0; it < 4; ++it) {
    int idx = t + it * 256;
    int r = idx >> 4, g = idx & 15;
    const unsigned short* tail =
        (const unsigned short*)(out + ((size_t)(b0 + r) * NNODE + n) * H + 64);
    short8 v = *(const short8*)(tail + g * 8);
    #pragma unroll
    for (int j = 0; j < 8; ++j) s_c[r * 132 + g * 8 + j] = b2f((unsigned short)v[j]);
  }
  __syncthreads();
  const int d = t & 31, rq = t >> 5;
  const float bias = out_b[n * FEAT + d];
  float accs[8];
  #pragma unroll
  for (int m = 0; m < 8; ++m) {
    int r = rq + 8 * m;
    float a = bias;
    #pragma unroll 8
    for (int k = 0; k < H; ++k) a += s_c[r * 132 + k] * s_wt[k * FEAT + d];
    accs[m] = a;
  }
  #pragma unroll
  for (int m = 0; m < 8; ++m) {
    int r = rq + 8 * m;
    out[((size_t)(b0 + r) * NNODE + n) * H + d] = accs[m];
  }
  #pragma unroll
  for (int q = 0; q < 6; ++q) {
    int idx = t + q * 256;
    int r = idx / 24, c4 = idx - r * 24;
    *(f32x4*)&out[((size_t)(b0 + r) * NNODE + n) * H + FEAT + c4 * 4] =
        f32x4{0.f, 0.f, 0.f, 0.f};
  }
}

extern "C" void kernel_launch(void* const* d_in, const int* in_sizes, int n_in,
                              void* d_out, int out_size, void* d_ws, size_t ws_size,
                              hipStream_t stream) {
  const float* x     = (const float*)d_in[0];
  const float* adj   = (const float*)d_in[1];
  const float* in_w  = (const float*)d_in[2];
  const float* in_b  = (const float*)d_in[3];
  const float* out_w = (const float*)d_in[4];
  const float* out_b = (const float*)d_in[5];
  const float* gc_w  = (const float*)d_in[6];
  const float* gc_b  = (const float*)d_in[7];
  const float* w_ih  = (const float*)d_in[8];
  const float* w_hh  = (const float*)d_in[9];
  const float* b_ih  = (const float*)d_in[10];
  const float* b_hh  = (const float*)d_in[11];
  (void)in_sizes; (void)n_in; (void)out_size;
  unsigned short* wimg = (unsigned short*)d_ws;   // ws_size >= 576KB (verified R3)
  hipLaunchKernelGGL(k_inemb, dim3(NBATCH), dim3(256), 0, stream, x, in_w, in_b, (float*)d_out);
  hipLaunchKernelGGL(k_prep, dim3(40), dim3(256), 0, stream, gc_w, w_ih, w_hh, wimg);
  hipLaunchKernelGGL(k_main, dim3(NBATCH), dim3(256), 0, stream,
                     adj, gc_b, b_ih, b_hh, wimg, (float*)d_out);
  hipLaunchKernelGGL(k_outemb, dim3(NBATCH), dim3(256), 0, stream, out_w, out_b, (float*)d_out);
}

// Round 6
// 826.723 us; speedup vs baseline: 2.2064x; 2.2064x over previous
//
#include <hip/hip_runtime.h>
#include <cstdint>

#define NBATCH 4096
#define NNODE  64
#define FEAT   32
#define H      128
#define NE     4
#define NL     3

typedef __attribute__((ext_vector_type(8))) short short8;
typedef __attribute__((ext_vector_type(4))) short short4v;
typedef __attribute__((ext_vector_type(4))) float f32x4;
typedef __attribute__((ext_vector_type(2))) float f32x2;

// ws image sizes
#define IMG_GC_ELEMS   (128 * 64)          // one (layer,edge,kh) image, shorts (16KB)
#define IMG_GRU_ELEMS  (48 * 128)          // one (mat,chunk) image, shorts (12KB)
#define IMG_GC_BYTES   (24 * IMG_GC_ELEMS * 2)    // 393216
#define IMG_GRU_BYTES  (16 * IMG_GRU_ELEMS * 2)   // 196608
#define WS_NEEDED      (IMG_GC_BYTES + IMG_GRU_BYTES)

__device__ __forceinline__ unsigned short f2b(float f) {
  union { float f; unsigned u; } v; v.f = f;
  unsigned u = v.u + 0x7FFFu + ((v.u >> 16) & 1u);   // RNE
  return (unsigned short)(u >> 16);
}
__device__ __forceinline__ float b2f(unsigned short s) {
  union { unsigned u; float f; } v; v.u = ((unsigned)s) << 16;
  return v.f;
}
__device__ __forceinline__ float sigm(float v) { return 1.0f / (1.0f + __expf(-v)); }
__device__ __forceinline__ float tanh_(float v) {
  v = fminf(fmaxf(v, -15.f), 15.f);
  float e = __expf(-2.f * v);
  return (1.f - e) / (1.f + e);
}
__device__ __forceinline__ int gidx128(int r, int g) { return r * 128 + ((g ^ (r & 7)) << 3); }
__device__ __forceinline__ int idx128(int r, int k) { return gidx128(r, k >> 3) + (k & 7); }
__device__ __forceinline__ int gidx64(int r, int g) { return r * 64 + (((g ^ (r & 7)) & 7) << 3); }

__device__ __forceinline__ short8 pack8(const float* v) {
  short8 r;
  #pragma unroll
  for (int j = 0; j < 8; ++j) r[j] = (short)f2b(v[j]);
  return r;
}

__device__ __forceinline__ void gll16(const void* g, void* l) {
  __builtin_amdgcn_global_load_lds(
      (const __attribute__((address_space(1))) unsigned int*)g,
      (__attribute__((address_space(3))) unsigned int*)l, 16, 0, 0);
}

// stage NIT*4 KiB image (NIT=4 -> 16KB, NIT=3 -> 12KB), all 4 waves
#define STAGE(dst, src, NIT)                                             \
  do {                                                                   \
    _Pragma("unroll")                                                    \
    for (int it_ = 0; it_ < (NIT); ++it_) {                              \
      int off_ = (it_ * 4 + w) * 1024;                                   \
      gll16((const char*)(src) + off_ + lane * 16, (char*)(dst) + off_); \
    }                                                                    \
  } while (0)

// ============ K0: build bf16 weight images in ws (exact swizzled LDS byte order) ========
__global__ __launch_bounds__(256, 2) void k_prep(
    const float* __restrict__ gc_w, const float* __restrict__ w_ih,
    const float* __restrict__ w_hh, unsigned short* __restrict__ ws)
{
  const int t = threadIdx.x;
  if (blockIdx.x < 24) {
    const int blk = blockIdx.x;
    const int kh = blk & 1, e = (blk >> 1) & 3, l = blk >> 3;
    const float* We = gc_w + (size_t)(l * NE + e) * H * H;
    unsigned short* dst = ws + (size_t)blk * IMG_GC_ELEMS;
    #pragma unroll
    for (int it = 0; it < 4; ++it) {
      int idx = t + it * 256;
      int r = idx >> 3, g = idx & 7;
      float v[8];
      #pragma unroll
      for (int j = 0; j < 8; ++j) v[j] = We[(kh * 64 + g * 8 + j) * H + r];
      *(short8*)&dst[gidx64(r, g)] = pack8(v);
    }
  } else {
    const int blk = blockIdx.x - 24;
    const int c = blk & 7, m = blk >> 3;
    const float* Mat = m ? w_hh : w_ih;
    unsigned short* dst = ws + IMG_GC_BYTES / 2 + (size_t)blk * IMG_GRU_ELEMS;
    #pragma unroll
    for (int it = 0; it < 3; ++it) {
      int idx = t + it * 256;
      int rr = idx >> 4, g = idx & 15;
      int mrow = (rr >> 4) * H + 16 * c + (rr & 15);
      float v[8];
      #pragma unroll
      for (int j = 0; j < 8; ++j) v[j] = Mat[mrow * H + g * 8 + j];
      *(short8*)&dst[gidx128(rr, g)] = pack8(v);
    }
  }
}

// ================= K1: per-node input embedding -> bf16 h0 in out-row tails =============
__global__ __launch_bounds__(256, 2) void k_inemb(
    const float* __restrict__ x, const float* __restrict__ in_w,
    const float* __restrict__ in_b, float* __restrict__ out)
{
  __shared__ float s_wt[FEAT * H];
  __shared__ float s_x[64 * FEAT];
  const int t = threadIdx.x;
  const int n = blockIdx.x >> 6, bt = blockIdx.x & 63, b0 = bt * 64;
  const float* wsrc = in_w + (size_t)n * FEAT * H;
  #pragma unroll
  for (int it = 0; it < 4; ++it) {
    int i4 = t + it * 256;
    *(f32x4*)&s_wt[i4 * 4] = *(const f32x4*)&wsrc[i4 * 4];
  }
  {
    int r = t >> 2, q = t & 3;
    const float* xs = x + ((size_t)(b0 + r) * NNODE + n) * FEAT;
    *(f32x4*)&s_x[r * 32 + q * 8]     = *(const f32x4*)&xs[q * 8];
    *(f32x4*)&s_x[r * 32 + q * 8 + 4] = *(const f32x4*)&xs[q * 8 + 4];
  }
  __syncthreads();
  const int h2 = t & 63, rp = t >> 6;
  const float bi0 = in_b[n * H + 2 * h2], bi1 = in_b[n * H + 2 * h2 + 1];
  #pragma unroll 1
  for (int m = 0; m < 16; ++m) {
    int r = rp + 4 * m;
    float a0 = bi0, a1 = bi1;
    #pragma unroll
    for (int d = 0; d < 32; ++d) {
      float xv = s_x[r * 32 + d];
      f32x2 wv = *(const f32x2*)&s_wt[d * H + 2 * h2];
      a0 += xv * wv.x; a1 += xv * wv.y;
    }
    unsigned p = (unsigned)f2b(a0) | ((unsigned)f2b(a1) << 16);
    unsigned short* tail = (unsigned short*)(out + ((size_t)(b0 + r) * NNODE + n) * H + 64);
    *(unsigned*)(tail + 2 * h2) = p;
  }
}

// ================= K2: 3 layers of RGCN + GRU, phase-pipelined MFMA, bounded pressure ====
__global__ __launch_bounds__(256, 2) void k_main(
    const float* __restrict__ adj,
    const float* __restrict__ gc_b,
    const float* __restrict__ b_ih, const float* __restrict__ b_hh,
    const unsigned short* __restrict__ wimg,
    float* __restrict__ out)
{
  __shared__ unsigned short s_cur[64 * 128];  // hidden (in-place per layer)
  __shared__ unsigned short s_u[128 * 64];    // S^T [h][j] / xf [i][h]
  __shared__ unsigned short s_w0[128 * 64];   // weight dbuf A
  __shared__ unsigned short s_w1[128 * 64];   // weight dbuf B
  __shared__ unsigned short s_adj[64 * 64];   // adj_e bf16 [i][j]
  __shared__ float s_bias[1280];              // gc_b layer slice | b_ih | b_hh

  const int t = threadIdx.x;
  const int b = blockIdx.x;
  const int w = t >> 6, lane = t & 63, lr = lane & 15, lq = lane >> 4;
  float* outb = out + (size_t)b * NNODE * H;
  const unsigned short* img_gru = wimg + IMG_GC_BYTES / 2;

  // ---- prologue: prefetch W(l0,e0,kh0); h0 from out-row tails; GRU biases ----
  STAGE(s_w0, wimg, 4);
  #pragma unroll
  for (int it = 0; it < 4; ++it) {
    int idx = t + it * 256;
    int n = idx >> 4, g = idx & 15;
    short8 v = *(const short8*)((const unsigned short*)(outb + n * H + 64) + g * 8);
    *(short8*)&s_cur[gidx128(n, g)] = v;
  }
  #pragma unroll
  for (int it = 0; it < 3; ++it) {
    int idx = t + it * 256;
    s_bias[512 + idx] = (idx < 384) ? b_ih[idx] : b_hh[idx - 384];
  }
  __syncthreads();

  #pragma unroll 1
  for (int layer = 0; layer < NL; ++layer) {
    f32x4 agg[8];
    #pragma unroll
    for (int tn = 0; tn < 8; ++tn) agg[tn] = f32x4{0.f, 0.f, 0.f, 0.f};

    // ======== edges: 3 barriers each; every stage issued one phase early ====
    #pragma unroll 1
    for (int e = 0; e < NE; ++e) {
      const unsigned short* img_e = wimg + (size_t)((layer * NE + e) * 2) * IMG_GC_ELEMS;
      const float* adj_e = adj + (((size_t)b * NE + e) * NNODE * NNODE);

      // ---- P2: issue W1<-kh1; stage adj->s_adj; mm1 kh0 from W0 ----
      STAGE(s_w1, img_e + IMG_GC_ELEMS, 4);
      if (e == 0) {  // this layer's gc_b slice (read at P4, after barrier)
        s_bias[t]       = gc_b[layer * 512 + t];
        s_bias[t + 256] = gc_b[layer * 512 + t + 256];
      }
      #pragma unroll
      for (int it = 0; it < 2; ++it) {
        int idx = t + it * 256;
        int i = idx >> 3, g = idx & 7;
        const float* src = adj_e + i * 64 + g * 8;
        float v[8];
        #pragma unroll
        for (int j = 0; j < 8; ++j) v[j] = src[j];
        *(short8*)&s_adj[gidx64(i, g)] = pack8(v);
      }
      f32x4 Sacc[8];
      #pragma unroll
      for (int tn = 0; tn < 8; ++tn) Sacc[tn] = f32x4{0.f, 0.f, 0.f, 0.f};
      #pragma unroll
      for (int ks = 0; ks < 2; ++ks) {
        short8 a = *(const short8*)&s_cur[gidx128(16 * w + lr, ks * 4 + lq)];
        #pragma unroll
        for (int tn = 0; tn < 8; ++tn) {
          short8 bb = *(const short8*)&s_w0[gidx64(16 * tn + lr, ks * 4 + lq)];
          Sacc[tn] = __builtin_amdgcn_mfma_f32_16x16x32_bf16(a, bb, Sacc[tn], 0, 0, 0);
        }
      }
      __syncthreads();   // W1 + s_adj ready (issue hidden under mm1 kh0)

      // ---- P3: issue W0<-next; mm1 kh1 from W1; pack S^T -> s_u ----
      if (e < 3) { STAGE(s_w0, img_e + 2 * IMG_GC_ELEMS, 4); }
      else       { STAGE(s_w0, img_gru, 3); }          // GRU ih(0)
      #pragma unroll
      for (int ks = 0; ks < 2; ++ks) {
        short8 a = *(const short8*)&s_cur[gidx128(16 * w + lr, 8 + ks * 4 + lq)];
        #pragma unroll
        for (int tn = 0; tn < 8; ++tn) {
          short8 bb = *(const short8*)&s_w1[gidx64(16 * tn + lr, ks * 4 + lq)];
          Sacc[tn] = __builtin_amdgcn_mfma_f32_16x16x32_bf16(a, bb, Sacc[tn], 0, 0, 0);
        }
      }
      {
        int nb = 16 * w + 4 * lq;
        int g = nb >> 3, sub = nb & 7;
        #pragma unroll
        for (int tn = 0; tn < 8; ++tn) {
          int h = 16 * tn + lr;
          short4v p;
          #pragma unroll
          for (int r = 0; r < 4; ++r) p[r] = (short)f2b(Sacc[tn][r]);
          *(short4v*)&s_u[gidx64(h, g) + sub] = p;
        }
      }
      __syncthreads();   // S^T visible; W0(next) ready

      // ---- P4: mm2 from s_adj x S^T; agg += relu ----
      {
        f32x4 Oacc[8];
        #pragma unroll
        for (int tn = 0; tn < 8; ++tn) Oacc[tn] = f32x4{0.f, 0.f, 0.f, 0.f};
        #pragma unroll
        for (int ks = 0; ks < 2; ++ks) {
          short8 a = *(const short8*)&s_adj[gidx64(16 * w + lr, ks * 4 + lq)];
          #pragma unroll
          for (int tn = 0; tn < 8; ++tn) {
            short8 bb = *(const short8*)&s_u[gidx64(16 * tn + lr, ks * 4 + lq)];
            Oacc[tn] = __builtin_amdgcn_mfma_f32_16x16x32_bf16(a, bb, Oacc[tn], 0, 0, 0);
          }
        }
        #pragma unroll
        for (int tn = 0; tn < 8; ++tn) {
          float bias = s_bias[e * 128 + 16 * tn + lr];
          #pragma unroll
          for (int r = 0; r < 4; ++r)
            agg[tn][r] += 0.25f * fmaxf(Oacc[tn][r] + bias, 0.f);
        }
      }
      __syncthreads();   // close s_u / s_adj reads
    }  // edges

    // ---- xf = agg -> s_u row-major [i][h] ----
    #pragma unroll
    for (int tn = 0; tn < 8; ++tn) {
      int h = 16 * tn + lr;
      #pragma unroll
      for (int r = 0; r < 4; ++r) {
        int i = 16 * w + 4 * lq + r;
        s_u[idx128(i, h)] = f2b(agg[tn][r]);
      }
    }
    __syncthreads();

    // ======== GRU: 8 chunks ROLLED; h' spills to out-row tails (block-private) ====
    #pragma unroll 1
    for (int c = 0; c < 8; ++c) {
      // Pgi: issue W1<-hh(c); gi(c) from W0 + xf
      STAGE(s_w1, img_gru + (size_t)(8 + c) * IMG_GRU_ELEMS, 3);
      f32x4 gi[3], gh[3];
      #pragma unroll
      for (int tg = 0; tg < 3; ++tg) gi[tg] = f32x4{0.f, 0.f, 0.f, 0.f};
      #pragma unroll
      for (int ks = 0; ks < 4; ++ks) {
        short8 bb = *(const short8*)&s_u[gidx128(16 * w + lr, ks * 4 + lq)];
        #pragma unroll
        for (int tg = 0; tg < 3; ++tg) {
          short8 a = *(const short8*)&s_w0[gidx128(16 * tg + lr, ks * 4 + lq)];
          gi[tg] = __builtin_amdgcn_mfma_f32_16x16x32_bf16(a, bb, gi[tg], 0, 0, 0);
        }
      }
      __syncthreads();   // W1/hh(c) ready (hidden under gi)

      // Pgh: issue W0<-ih(c+1) | next-layer GC(e0,kh0); gh(c) from W1 + cur; gates
      if (c < 7)          { STAGE(s_w0, img_gru + (size_t)(c + 1) * IMG_GRU_ELEMS, 3); }
      else if (layer < 2) { STAGE(s_w0, wimg + (size_t)((layer + 1) * NE * 2) * IMG_GC_ELEMS, 4); }
      #pragma unroll
      for (int tg = 0; tg < 3; ++tg) gh[tg] = f32x4{0.f, 0.f, 0.f, 0.f};
      #pragma unroll
      for (int ks = 0; ks < 4; ++ks) {
        short8 bb = *(const short8*)&s_cur[gidx128(16 * w + lr, ks * 4 + lq)];
        #pragma unroll
        for (int tg = 0; tg < 3; ++tg) {
          short8 a = *(const short8*)&s_w1[gidx128(16 * tg + lr, ks * 4 + lq)];
          gh[tg] = __builtin_amdgcn_mfma_f32_16x16x32_bf16(a, bb, gh[tg], 0, 0, 0);
        }
      }
      {
        int i = 16 * w + lr;
        int g = (16 * c + 4 * lq) >> 3;
        int off = gidx128(i, g) + ((4 * lq) & 7);
        short4v hv = *(const short4v*)&s_cur[off];
        short4v hp;
        #pragma unroll
        for (int r = 0; r < 4; ++r) {
          int mH = 16 * c + 4 * lq + r;
          float rg = sigm(gi[0][r] + s_bias[512 + mH] + gh[0][r] + s_bias[896 + mH]);
          float zg = sigm(gi[1][r] + s_bias[640 + mH] + gh[1][r] + s_bias[1024 + mH]);
          float ng = tanh_(gi[2][r] + s_bias[768 + mH] + rg * (gh[2][r] + s_bias[1152 + mH]));
          float hold = b2f((unsigned short)hv[r]);
          hp[r] = (short)f2b((1.f - zg) * ng + zg * hold);
        }
        unsigned short* tail = (unsigned short*)(outb + (size_t)i * H + 64);
        *(short4v*)(tail + 16 * c + 4 * lq) = hp;   // h'(c) spill (layer 2: final output)
      }
      __syncthreads();   // close gh(c) cur/W1 reads
    }  // chunks

    // reload h' -> s_cur (block-private lines, L2-hot); skip for last layer
    if (layer < 2) {
      #pragma unroll
      for (int it = 0; it < 4; ++it) {
        int idx = t + it * 256;
        int n = idx >> 4, g = idx & 15;
        short8 v = *(const short8*)((const unsigned short*)(outb + n * H + 64) + g * 8);
        *(short8*)&s_cur[gidx128(n, g)] = v;
      }
      __syncthreads();
    }
  }  // layers
}

// ================= K3: per-node output embedding + zero pad =============
__global__ __launch_bounds__(256, 2) void k_outemb(
    const float* __restrict__ out_w, const float* __restrict__ out_b,
    float* __restrict__ out)
{
  __shared__ float s_wt[H * FEAT];
  __shared__ float s_c[64 * 132];
  const int t = threadIdx.x;
  const int n = blockIdx.x >> 6, bt = blockIdx.x & 63, b0 = bt * 64;
  const float* wsrc = out_w + (size_t)n * H * FEAT;
  #pragma unroll
  for (int it = 0; it < 4; ++it) {
    int i4 = t + it * 256;
    *(f32x4*)&s_wt[i4 * 4] = *(const f32x4*)&wsrc[i4 * 4];
  }
  #pragma unroll
  for (int it = 0; it < 4; ++it) {
    int idx = t + it * 256;
    int r = idx >> 4, g = idx & 15;
    const unsigned short* tail =
        (const unsigned short*)(out + ((size_t)(b0 + r) * NNODE + n) * H + 64);
    short8 v = *(const short8*)(tail + g * 8);
    #pragma unroll
    for (int j = 0; j < 8; ++j) s_c[r * 132 + g * 8 + j] = b2f((unsigned short)v[j]);
  }
  __syncthreads();
  const int d = t & 31, rq = t >> 5;
  const float bias = out_b[n * FEAT + d];
  float accs[8];
  #pragma unroll
  for (int m = 0; m < 8; ++m) {
    int r = rq + 8 * m;
    float a = bias;
    #pragma unroll 8
    for (int k = 0; k < H; ++k) a += s_c[r * 132 + k] * s_wt[k * FEAT + d];
    accs[m] = a;
  }
  #pragma unroll
  for (int m = 0; m < 8; ++m) {
    int r = rq + 8 * m;
    out[((size_t)(b0 + r) * NNODE + n) * H + d] = accs[m];
  }
  #pragma unroll
  for (int q = 0; q < 6; ++q) {
    int idx = t + q * 256;
    int r = idx / 24, c4 = idx - r * 24;
    *(f32x4*)&out[((size_t)(b0 + r) * NNODE + n) * H + FEAT + c4 * 4] =
        f32x4{0.f, 0.f, 0.f, 0.f};
  }
}

extern "C" void kernel_launch(void* const* d_in, const int* in_sizes, int n_in,
                              void* d_out, int out_size, void* d_ws, size_t ws_size,
                              hipStream_t stream) {
  const float* x     = (const float*)d_in[0];
  const float* adj   = (const float*)d_in[1];
  const float* in_w  = (const float*)d_in[2];
  const float* in_b  = (const float*)d_in[3];
  const float* out_w = (const float*)d_in[4];
  const float* out_b = (const float*)d_in[5];
  const float* gc_w  = (const float*)d_in[6];
  const float* gc_b  = (const float*)d_in[7];
  const float* w_ih  = (const float*)d_in[8];
  const float* w_hh  = (const float*)d_in[9];
  const float* b_ih  = (const float*)d_in[10];
  const float* b_hh  = (const float*)d_in[11];
  (void)in_sizes; (void)n_in; (void)out_size;
  unsigned short* wimg = (unsigned short*)d_ws;   // ws_size >= 576KB (verified R3)
  hipLaunchKernelGGL(k_inemb, dim3(NBATCH), dim3(256), 0, stream, x, in_w, in_b, (float*)d_out);
  hipLaunchKernelGGL(k_prep, dim3(40), dim3(256), 0, stream, gc_w, w_ih, w_hh, wimg);
  hipLaunchKernelGGL(k_main, dim3(NBATCH), dim3(256), 0, stream,
                     adj, gc_b, b_ih, b_hh, wimg, (float*)d_out);
  hipLaunchKernelGGL(k_outemb, dim3(NBATCH), dim3(256), 0, stream, out_w, out_b, (float*)d_out);
}

// Round 7
// 823.820 us; speedup vs baseline: 2.2142x; 1.0035x over previous
//
#include <hip/hip_runtime.h>
#include <cstdint>

#define NBATCH 4096
#define NNODE  64
#define FEAT   32
#define H      128
#define NE     4
#define NL     3

typedef __attribute__((ext_vector_type(8))) short short8;
typedef __attribute__((ext_vector_type(4))) short short4v;
typedef __attribute__((ext_vector_type(4))) float f32x4;
typedef __attribute__((ext_vector_type(2))) float f32x2;
typedef unsigned long long u64;

// ws layout: [0,576KB) weight images; [576KB, +134MB) adj bf16 images (optional)
#define IMG_GC_ELEMS   (128 * 64)
#define IMG_GRU_ELEMS  (48 * 128)
#define IMG_GC_BYTES   (24 * IMG_GC_ELEMS * 2)    // 393216
#define IMG_GRU_BYTES  (16 * IMG_GRU_ELEMS * 2)   // 196608
#define WS_W_BYTES     (IMG_GC_BYTES + IMG_GRU_BYTES)
#define WIMG_SHORTS    (WS_W_BYTES / 2)
#define ADJ_IMG_ELEMS  4096                        // 64*64 shorts per (b,e)
#define WS_FULL ((size_t)WS_W_BYTES + (size_t)NBATCH * NE * ADJ_IMG_ELEMS * 2)

__device__ __forceinline__ unsigned short f2b(float f) {
  union { float f; unsigned u; } v; v.f = f;
  unsigned u = v.u + 0x7FFFu + ((v.u >> 16) & 1u);   // RNE
  return (unsigned short)(u >> 16);
}
__device__ __forceinline__ float b2f(unsigned short s) {
  union { unsigned u; float f; } v; v.u = ((unsigned)s) << 16;
  return v.f;
}
__device__ __forceinline__ unsigned cvtpk(float lo, float hi) {
  unsigned r;
  asm volatile("v_cvt_pk_bf16_f32 %0, %1, %2" : "=v"(r) : "v"(lo), "v"(hi));
  return r;
}
__device__ __forceinline__ float sigm(float v) { return 1.0f / (1.0f + __expf(-v)); }
__device__ __forceinline__ float tanh_(float v) {
  v = fminf(fmaxf(v, -15.f), 15.f);
  float e = __expf(-2.f * v);
  return (1.f - e) / (1.f + e);
}
__device__ __forceinline__ int gidx128(int r, int g) { return r * 128 + ((g ^ (r & 7)) << 3); }
__device__ __forceinline__ int idx128(int r, int k) { return gidx128(r, k >> 3) + (k & 7); }
__device__ __forceinline__ int gidx64(int r, int g) { return r * 64 + (((g ^ (r & 7)) & 7) << 3); }

__device__ __forceinline__ short8 pack8f(const float* v) {
  union { unsigned u[4]; short8 s; } r;
  r.u[0] = cvtpk(v[0], v[1]); r.u[1] = cvtpk(v[2], v[3]);
  r.u[2] = cvtpk(v[4], v[5]); r.u[3] = cvtpk(v[6], v[7]);
  return r.s;
}

__device__ __forceinline__ void gll16(const void* g, void* l) {
  __builtin_amdgcn_global_load_lds(
      (const __attribute__((address_space(1))) unsigned int*)g,
      (__attribute__((address_space(3))) unsigned int*)l, 16, 0, 0);
}

// stage NIT*4 KiB image, all 4 waves
#define STAGE(dst, src, NIT)                                             \
  do {                                                                   \
    _Pragma("unroll")                                                    \
    for (int it_ = 0; it_ < (NIT); ++it_) {                              \
      int off_ = (it_ * 4 + w) * 1024;                                   \
      gll16((const char*)(src) + off_ + lane * 16, (char*)(dst) + off_); \
    }                                                                    \
  } while (0)

// raw barrier: LDS visibility only (NO vmcnt drain — that's the point)
#define BAR() do { asm volatile("s_waitcnt lgkmcnt(0)" ::: "memory"); \
                   __builtin_amdgcn_s_barrier(); } while (0)
// counted vmem wait + scheduling fence (rule #18)
#define VMW(N) do { asm volatile("s_waitcnt vmcnt(" #N ")" ::: "memory"); \
                    __builtin_amdgcn_sched_barrier(0); } while (0)
#define SB0() __builtin_amdgcn_sched_barrier(0)

// ============ K0: bf16 weight images in ws (exact swizzled LDS byte order) ========
__global__ __launch_bounds__(256, 2) void k_prep(
    const float* __restrict__ gc_w, const float* __restrict__ w_ih,
    const float* __restrict__ w_hh, unsigned short* __restrict__ ws)
{
  const int t = threadIdx.x;
  if (blockIdx.x < 24) {
    const int blk = blockIdx.x;
    const int kh = blk & 1, e = (blk >> 1) & 3, l = blk >> 3;
    const float* We = gc_w + (size_t)(l * NE + e) * H * H;
    unsigned short* dst = ws + (size_t)blk * IMG_GC_ELEMS;
    #pragma unroll
    for (int it = 0; it < 4; ++it) {
      int idx = t + it * 256;
      int r = idx >> 3, g = idx & 7;
      float v[8];
      #pragma unroll
      for (int j = 0; j < 8; ++j) v[j] = We[(kh * 64 + g * 8 + j) * H + r];
      *(short8*)&dst[gidx64(r, g)] = pack8f(v);
    }
  } else {
    const int blk = blockIdx.x - 24;
    const int c = blk & 7, m = blk >> 3;
    const float* Mat = m ? w_hh : w_ih;
    unsigned short* dst = ws + WIMG_SHORTS - IMG_GRU_BYTES / 2 + (size_t)blk * IMG_GRU_ELEMS;
    #pragma unroll
    for (int it = 0; it < 3; ++it) {
      int idx = t + it * 256;
      int rr = idx >> 4, g = idx & 15;
      int mrow = (rr >> 4) * H + 16 * c + (rr & 15);
      float v[8];
      #pragma unroll
      for (int j = 0; j < 8; ++j) v[j] = Mat[mrow * H + g * 8 + j];
      *(short8*)&dst[gidx128(rr, g)] = pack8f(v);
    }
  }
}

// ============ K1: input embedding -> bf16 h0 tails; plus adj->bf16 images ==========
template <bool ADJIMG>
__global__ __launch_bounds__(256, 2) void k_inemb(
    const float* __restrict__ x, const float* __restrict__ in_w,
    const float* __restrict__ in_b, const float* __restrict__ adj,
    unsigned short* __restrict__ ws, float* __restrict__ out)
{
  __shared__ float s_wt[FEAT * H];
  __shared__ float s_x[64 * FEAT];
  const int t = threadIdx.x;
  const int n = blockIdx.x >> 6, bt = blockIdx.x & 63, b0 = bt * 64;
  const float* wsrc = in_w + (size_t)n * FEAT * H;
  #pragma unroll
  for (int it = 0; it < 4; ++it) {
    int i4 = t + it * 256;
    *(f32x4*)&s_wt[i4 * 4] = *(const f32x4*)&wsrc[i4 * 4];
  }
  {
    int r = t >> 2, q = t & 3;
    const float* xs = x + ((size_t)(b0 + r) * NNODE + n) * FEAT;
    *(f32x4*)&s_x[r * 32 + q * 8]     = *(const f32x4*)&xs[q * 8];
    *(f32x4*)&s_x[r * 32 + q * 8 + 4] = *(const f32x4*)&xs[q * 8 + 4];
  }
  __syncthreads();
  const int h2 = t & 63, rp = t >> 6;
  const float bi0 = in_b[n * H + 2 * h2], bi1 = in_b[n * H + 2 * h2 + 1];
  #pragma unroll 1
  for (int m = 0; m < 16; ++m) {
    int r = rp + 4 * m;
    float a0 = bi0, a1 = bi1;
    #pragma unroll
    for (int d = 0; d < 32; ++d) {
      float xv = s_x[r * 32 + d];
      f32x2 wv = *(const f32x2*)&s_wt[d * H + 2 * h2];
      a0 += xv * wv.x; a1 += xv * wv.y;
    }
    unsigned p = cvtpk(a0, a1);
    unsigned short* tail = (unsigned short*)(out + ((size_t)(b0 + r) * NNODE + n) * H + 64);
    *(unsigned*)(tail + 2 * h2) = p;
  }
  if (ADJIMG) {
    // convert this block's b = blockIdx.x adjacency to bf16 swizzled images
    const float* ab = adj + (size_t)blockIdx.x * NE * NNODE * NNODE;
    unsigned short* dst = ws + WIMG_SHORTS + (size_t)blockIdx.x * NE * ADJ_IMG_ELEMS;
    #pragma unroll 1
    for (int q = 0; q < 8; ++q) {
      int gi = t + q * 256;                 // 0..2047
      int e = gi >> 9, idx = gi & 511, r = idx >> 3, g = idx & 7;
      const float* src = ab + e * 4096 + r * 64 + g * 8;
      float v[8];
      #pragma unroll
      for (int j = 0; j < 8; ++j) v[j] = src[j];
      *(short8*)&dst[e * ADJ_IMG_ELEMS + gidx64(r, g)] = pack8f(v);
    }
  }
}

// ================= K2: RGCN+GRU, counted-vmcnt phase pipeline =============
template <bool ADJIMG>
__global__ __launch_bounds__(256, 2) void k_main(
    const float* __restrict__ adj,
    const float* __restrict__ gc_b,
    const float* __restrict__ b_ih, const float* __restrict__ b_hh,
    const unsigned short* __restrict__ wimg,
    float* __restrict__ out)
{
  __shared__ unsigned short s_cur[64 * 128];
  __shared__ unsigned short s_u[128 * 64];
  __shared__ unsigned short s_w0[128 * 64];
  __shared__ unsigned short s_w1[128 * 64];
  __shared__ unsigned short s_adj[64 * 64];
  __shared__ float s_bias[1280];

  const int t = threadIdx.x;
  const int b = blockIdx.x;
  const int w = t >> 6, lane = t & 63, lr = lane & 15, lq = lane >> 4;
  float* outb = out + (size_t)b * NNODE * H;
  const unsigned short* img_gru = wimg + WIMG_SHORTS - IMG_GRU_BYTES / 2;
  const unsigned short* aimg = wimg + WIMG_SHORTS + (size_t)b * NE * ADJ_IMG_ELEMS;

  // ---- prologue (full drain via __syncthreads) ----
  STAGE(s_w0, wimg, 4);
  #pragma unroll
  for (int it = 0; it < 4; ++it) {
    int idx = t + it * 256;
    int n = idx >> 4, g = idx & 15;
    short8 v = *(const short8*)((const unsigned short*)(outb + n * H + 64) + g * 8);
    *(short8*)&s_cur[gidx128(n, g)] = v;
  }
  #pragma unroll
  for (int it = 0; it < 3; ++it) {
    int idx = t + it * 256;
    s_bias[512 + idx] = (idx < 384) ? b_ih[idx] : b_hh[idx - 384];
  }
  __syncthreads();

  #pragma unroll 1
  for (int layer = 0; layer < NL; ++layer) {
    f32x4 agg[8];
    #pragma unroll
    for (int tn = 0; tn < 8; ++tn) agg[tn] = f32x4{0.f, 0.f, 0.f, 0.f};

    // ======== edges: raw barriers + ledgered vmcnt ====
    #pragma unroll 1
    for (int e = 0; e < NE; ++e) {
      const unsigned short* img_e = wimg + (size_t)((layer * NE + e) * 2) * IMG_GC_ELEMS;

      // ---- P2: [gc_b @ e0]; issue W1<-kh1 [4]; issue adj [2]; mm1-kh0(W0) ----
      if (e == 0) {
        s_bias[t]       = gc_b[layer * 512 + t];
        s_bias[t + 256] = gc_b[layer * 512 + t + 256];
      }
      STAGE(s_w1, img_e + IMG_GC_ELEMS, 4);
      SB0();                                  // pin order: W1 older than adj
      if (ADJIMG) {
        STAGE(s_adj, aimg + (size_t)e * ADJ_IMG_ELEMS, 2);
        SB0();
      } else {
        const float* adj_e = adj + (((size_t)b * NE + e) * NNODE * NNODE);
        #pragma unroll
        for (int it = 0; it < 2; ++it) {
          int idx = t + it * 256;
          int i = idx >> 3, g = idx & 7;
          const float* src = adj_e + i * 64 + g * 8;
          float v[8];
          #pragma unroll
          for (int j = 0; j < 8; ++j) v[j] = src[j];
          *(short8*)&s_adj[gidx64(i, g)] = pack8f(v);
        }
      }
      f32x4 Sacc[8];
      #pragma unroll
      for (int tn = 0; tn < 8; ++tn) Sacc[tn] = f32x4{0.f, 0.f, 0.f, 0.f};
      __builtin_amdgcn_s_setprio(1);
      #pragma unroll
      for (int ks = 0; ks < 2; ++ks) {
        short8 a = *(const short8*)&s_cur[gidx128(16 * w + lr, ks * 4 + lq)];
        #pragma unroll
        for (int tn = 0; tn < 8; ++tn) {
          short8 bb = *(const short8*)&s_w0[gidx64(16 * tn + lr, ks * 4 + lq)];
          Sacc[tn] = __builtin_amdgcn_mfma_f32_16x16x32_bf16(a, bb, Sacc[tn], 0, 0, 0);
        }
      }
      __builtin_amdgcn_s_setprio(0);
      if (ADJIMG) { VMW(2); }   // W1 done; adj keeps flying
      else        { VMW(0); }   // only W1 outstanding
      BAR();

      // ---- P3: issue W0<-next [4|3]; mm1-kh1(W1); pack S^T -> s_u ----
      if (e < 3) { STAGE(s_w0, img_e + 2 * IMG_GC_ELEMS, 4); }
      else       { STAGE(s_w0, img_gru, 3); }
      SB0();
      __builtin_amdgcn_s_setprio(1);
      #pragma unroll
      for (int ks = 0; ks < 2; ++ks) {
        short8 a = *(const short8*)&s_cur[gidx128(16 * w + lr, 8 + ks * 4 + lq)];
        #pragma unroll
        for (int tn = 0; tn < 8; ++tn) {
          short8 bb = *(const short8*)&s_w1[gidx64(16 * tn + lr, ks * 4 + lq)];
          Sacc[tn] = __builtin_amdgcn_mfma_f32_16x16x32_bf16(a, bb, Sacc[tn], 0, 0, 0);
        }
      }
      __builtin_amdgcn_s_setprio(0);
      {
        int nb = 16 * w + 4 * lq;
        int g = nb >> 3, sub = nb & 7;
        #pragma unroll
        for (int tn = 0; tn < 8; ++tn) {
          int h = 16 * tn + lr;
          u64 pv = (u64)cvtpk(Sacc[tn][0], Sacc[tn][1]) |
                   ((u64)cvtpk(Sacc[tn][2], Sacc[tn][3]) << 32);
          *(u64*)&s_u[gidx64(h, g) + sub] = pv;
        }
      }
      VMW(4);                  // adj drained; W0next keeps flying
      BAR();

      // ---- P4: mm2 (s_adj x S^T); agg += relu ----
      {
        f32x4 Oacc[8];
        #pragma unroll
        for (int tn = 0; tn < 8; ++tn) Oacc[tn] = f32x4{0.f, 0.f, 0.f, 0.f};
        __builtin_amdgcn_s_setprio(1);
        #pragma unroll
        for (int ks = 0; ks < 2; ++ks) {
          short8 a = *(const short8*)&s_adj[gidx64(16 * w + lr, ks * 4 + lq)];
          #pragma unroll
          for (int tn = 0; tn < 8; ++tn) {
            short8 bb = *(const short8*)&s_u[gidx64(16 * tn + lr, ks * 4 + lq)];
            Oacc[tn] = __builtin_amdgcn_mfma_f32_16x16x32_bf16(a, bb, Oacc[tn], 0, 0, 0);
          }
        }
        __builtin_amdgcn_s_setprio(0);
        #pragma unroll
        for (int tn = 0; tn < 8; ++tn) {
          float bias = s_bias[e * 128 + 16 * tn + lr];
          #pragma unroll
          for (int r = 0; r < 4; ++r)
            agg[tn][r] += 0.25f * fmaxf(Oacc[tn][r] + bias, 0.f);
        }
      }
      VMW(0);                  // W0next ready for next P2 / GRU
      BAR();
    }  // edges

    // ---- xf = agg -> s_u row-major [i][h] ----
    #pragma unroll
    for (int tn = 0; tn < 8; ++tn) {
      int h = 16 * tn + lr;
      #pragma unroll
      for (int r = 0; r < 4; ++r) {
        int i = 16 * w + 4 * lq + r;
        s_u[idx128(i, h)] = f2b(agg[tn][r]);
      }
    }
    BAR();

    // ======== GRU: R6 structure (__syncthreads), + setprio ====
    #pragma unroll 1
    for (int c = 0; c < 8; ++c) {
      STAGE(s_w1, img_gru + (size_t)(8 + c) * IMG_GRU_ELEMS, 3);
      f32x4 gi[3], gh[3];
      #pragma unroll
      for (int tg = 0; tg < 3; ++tg) gi[tg] = f32x4{0.f, 0.f, 0.f, 0.f};
      __builtin_amdgcn_s_setprio(1);
      #pragma unroll
      for (int ks = 0; ks < 4; ++ks) {
        short8 bb = *(const short8*)&s_u[gidx128(16 * w + lr, ks * 4 + lq)];
        #pragma unroll
        for (int tg = 0; tg < 3; ++tg) {
          short8 a = *(const short8*)&s_w0[gidx128(16 * tg + lr, ks * 4 + lq)];
          gi[tg] = __builtin_amdgcn_mfma_f32_16x16x32_bf16(a, bb, gi[tg], 0, 0, 0);
        }
      }
      __builtin_amdgcn_s_setprio(0);
      __syncthreads();

      if (c < 7)          { STAGE(s_w0, img_gru + (size_t)(c + 1) * IMG_GRU_ELEMS, 3); }
      else if (layer < 2) { STAGE(s_w0, wimg + (size_t)((layer + 1) * NE * 2) * IMG_GC_ELEMS, 4); }
      #pragma unroll
      for (int tg = 0; tg < 3; ++tg) gh[tg] = f32x4{0.f, 0.f, 0.f, 0.f};
      __builtin_amdgcn_s_setprio(1);
      #pragma unroll
      for (int ks = 0; ks < 4; ++ks) {
        short8 bb = *(const short8*)&s_cur[gidx128(16 * w + lr, ks * 4 + lq)];
        #pragma unroll
        for (int tg = 0; tg < 3; ++tg) {
          short8 a = *(const short8*)&s_w1[gidx128(16 * tg + lr, ks * 4 + lq)];
          gh[tg] = __builtin_amdgcn_mfma_f32_16x16x32_bf16(a, bb, gh[tg], 0, 0, 0);
        }
      }
      __builtin_amdgcn_s_setprio(0);
      {
        int i = 16 * w + lr;
        int g = (16 * c + 4 * lq) >> 3;
        int off = gidx128(i, g) + ((4 * lq) & 7);
        short4v hv = *(const short4v*)&s_cur[off];
        float hf[4];
        #pragma unroll
        for (int r = 0; r < 4; ++r) {
          int mH = 16 * c + 4 * lq + r;
          float rg = sigm(gi[0][r] + s_bias[512 + mH] + gh[0][r] + s_bias[896 + mH]);
          float zg = sigm(gi[1][r] + s_bias[640 + mH] + gh[1][r] + s_bias[1024 + mH]);
          float ng = tanh_(gi[2][r] + s_bias[768 + mH] + rg * (gh[2][r] + s_bias[1152 + mH]));
          float hold = b2f((unsigned short)hv[r]);
          hf[r] = (1.f - zg) * ng + zg * hold;
        }
        u64 hp = (u64)cvtpk(hf[0], hf[1]) | ((u64)cvtpk(hf[2], hf[3]) << 32);
        unsigned short* tail = (unsigned short*)(outb + (size_t)i * H + 64);
        *(u64*)(tail + 16 * c + 4 * lq) = hp;
      }
      __syncthreads();
    }  // chunks

    if (layer < 2) {
      #pragma unroll
      for (int it = 0; it < 4; ++it) {
        int idx = t + it * 256;
        int n = idx >> 4, g = idx & 15;
        short8 v = *(const short8*)((const unsigned short*)(outb + n * H + 64) + g * 8);
        *(short8*)&s_cur[gidx128(n, g)] = v;
      }
      __syncthreads();
    }
  }  // layers
}

// ================= K3: output embedding + zero pad =============
__global__ __launch_bounds__(256, 2) void k_outemb(
    const float* __restrict__ out_w, const float* __restrict__ out_b,
    float* __restrict__ out)
{
  __shared__ float s_wt[H * FEAT];
  __shared__ float s_c[64 * 132];
  const int t = threadIdx.x;
  const int n = blockIdx.x >> 6, bt = blockIdx.x & 63, b0 = bt * 64;
  const float* wsrc = out_w + (size_t)n * H * FEAT;
  #pragma unroll
  for (int it = 0; it < 4; ++it) {
    int i4 = t + it * 256;
    *(f32x4*)&s_wt[i4 * 4] = *(const f32x4*)&wsrc[i4 * 4];
  }
  #pragma unroll
  for (int it = 0; it < 4; ++it) {
    int idx = t + it * 256;
    int r = idx >> 4, g = idx & 15;
    const unsigned short* tail =
        (const unsigned short*)(out + ((size_t)(b0 + r) * NNODE + n) * H + 64);
    short8 v = *(const short8*)(tail + g * 8);
    #pragma unroll
    for (int j = 0; j < 8; ++j) s_c[r * 132 + g * 8 + j] = b2f((unsigned short)v[j]);
  }
  __syncthreads();
  const int d = t & 31, rq = t >> 5;
  const float bias = out_b[n * FEAT + d];
  float accs[8];
  #pragma unroll
  for (int m = 0; m < 8; ++m) {
    int r = rq + 8 * m;
    float a = bias;
    #pragma unroll 8
    for (int k = 0; k < H; ++k) a += s_c[r * 132 + k] * s_wt[k * FEAT + d];
    accs[m] = a;
  }
  #pragma unroll
  for (int m = 0; m < 8; ++m) {
    int r = rq + 8 * m;
    out[((size_t)(b0 + r) * NNODE + n) * H + d] = accs[m];
  }
  #pragma unroll
  for (int q = 0; q < 6; ++q) {
    int idx = t + q * 256;
    int r = idx / 24, c4 = idx - r * 24;
    *(f32x4*)&out[((size_t)(b0 + r) * NNODE + n) * H + FEAT + c4 * 4] =
        f32x4{0.f, 0.f, 0.f, 0.f};
  }
}

extern "C" void kernel_launch(void* const* d_in, const int* in_sizes, int n_in,
                              void* d_out, int out_size, void* d_ws, size_t ws_size,
                              hipStream_t stream) {
  const float* x     = (const float*)d_in[0];
  const float* adj   = (const float*)d_in[1];
  const float* in_w  = (const float*)d_in[2];
  const float* in_b  = (const float*)d_in[3];
  const float* out_w = (const float*)d_in[4];
  const float* out_b = (const float*)d_in[5];
  const float* gc_w  = (const float*)d_in[6];
  const float* gc_b  = (const float*)d_in[7];
  const float* w_ih  = (const float*)d_in[8];
  const float* w_hh  = (const float*)d_in[9];
  const float* b_ih  = (const float*)d_in[10];
  const float* b_hh  = (const float*)d_in[11];
  (void)in_sizes; (void)n_in; (void)out_size;
  unsigned short* wimg = (unsigned short*)d_ws;      // >= 576KB verified (R3)
  const bool full = ws_size >= WS_FULL;
  hipLaunchKernelGGL(k_prep, dim3(40), dim3(256), 0, stream, gc_w, w_ih, w_hh, wimg);
  if (full) {
    hipLaunchKernelGGL(k_inemb<true>, dim3(NBATCH), dim3(256), 0, stream,
                       x, in_w, in_b, adj, wimg, (float*)d_out);
    hipLaunchKernelGGL(k_main<true>, dim3(NBATCH), dim3(256), 0, stream,
                       adj, gc_b, b_ih, b_hh, wimg, (float*)d_out);
  } else {
    hipLaunchKernelGGL(k_inemb<false>, dim3(NBATCH), dim3(256), 0, stream,
                       x, in_w, in_b, adj, wimg, (float*)d_out);
    hipLaunchKernelGGL(k_main<false>, dim3(NBATCH), dim3(256), 0, stream,
                       adj, gc_b, b_ih, b_hh, wimg, (float*)d_out);
  }
  hipLaunchKernelGGL(k_outemb, dim3(NBATCH), dim3(256), 0, stream, out_w, out_b, (float*)d_out);
}

// Round 8
// 763.930 us; speedup vs baseline: 2.3877x; 1.0784x over previous
//
#include <hip/hip_runtime.h>
#include <cstdint>

#define NBATCH 4096
#define NNODE  64
#define FEAT   32
#define H      128
#define NE     4
#define NL     3

typedef __attribute__((ext_vector_type(8))) short short8;
typedef __attribute__((ext_vector_type(4))) short short4v;
typedef __attribute__((ext_vector_type(4))) float f32x4;
typedef __attribute__((ext_vector_type(2))) float f32x2;
typedef unsigned long long u64;
typedef unsigned short ushort;

// ws layout: [0,576KB) weight images; then adj bf16 images (134MB)
#define IMG_GC_ELEMS   (128 * 64)
#define IMG_GRU_ELEMS  (48 * 128)
#define IMG_GC_BYTES   (24 * IMG_GC_ELEMS * 2)
#define IMG_GRU_BYTES  (16 * IMG_GRU_ELEMS * 2)
#define WS_W_BYTES     (IMG_GC_BYTES + IMG_GRU_BYTES)
#define WIMG_SHORTS    (WS_W_BYTES / 2)
#define ADJ_IMG_ELEMS  4096
#define WS_FULL ((size_t)WS_W_BYTES + (size_t)NBATCH * NE * ADJ_IMG_ELEMS * 2)

__device__ __forceinline__ ushort f2b(float f) {
  union { float f; unsigned u; } v; v.f = f;
  unsigned u = v.u + 0x7FFFu + ((v.u >> 16) & 1u);
  return (ushort)(u >> 16);
}
__device__ __forceinline__ float b2f(ushort s) {
  union { unsigned u; float f; } v; v.u = ((unsigned)s) << 16;
  return v.f;
}
__device__ __forceinline__ unsigned cvtpk(float lo, float hi) {
  unsigned r;
  asm volatile("v_cvt_pk_bf16_f32 %0, %1, %2" : "=v"(r) : "v"(lo), "v"(hi));
  return r;
}
__device__ __forceinline__ u64 pk4(float a, float b, float c, float d) {
  return (u64)cvtpk(a, b) | ((u64)cvtpk(c, d) << 32);
}
__device__ __forceinline__ float sigm(float v) { return 1.0f / (1.0f + __expf(-v)); }
__device__ __forceinline__ float tanh_(float v) {
  v = fminf(fmaxf(v, -15.f), 15.f);
  float e = __expf(-2.f * v);
  return (1.f - e) / (1.f + e);
}
__device__ __forceinline__ int gidx128(int r, int g) { return r * 128 + ((g ^ (r & 7)) << 3); }
__device__ __forceinline__ int idx128(int r, int k) { return gidx128(r, k >> 3) + (k & 7); }
__device__ __forceinline__ int gidx64(int r, int g) { return r * 64 + (((g ^ (r & 7)) & 7) << 3); }

__device__ __forceinline__ short8 pack8f(const float* v) {
  union { unsigned u[4]; short8 s; } r;
  r.u[0] = cvtpk(v[0], v[1]); r.u[1] = cvtpk(v[2], v[3]);
  r.u[2] = cvtpk(v[4], v[5]); r.u[3] = cvtpk(v[6], v[7]);
  return r.s;
}

__device__ __forceinline__ void gll16(const void* g, void* l) {
  __builtin_amdgcn_global_load_lds(
      (const __attribute__((address_space(1))) unsigned int*)g,
      (__attribute__((address_space(3))) unsigned int*)l, 16, 0, 0);
}

#define STAGE(dst, src, NIT)                                             \
  do {                                                                   \
    _Pragma("unroll")                                                    \
    for (int it_ = 0; it_ < (NIT); ++it_) {                              \
      int off_ = (it_ * 4 + w) * 1024;                                   \
      gll16((const char*)(src) + off_ + lane * 16, (char*)(dst) + off_); \
    }                                                                    \
  } while (0)

#define BAR() do { asm volatile("s_waitcnt lgkmcnt(0)" ::: "memory"); \
                   __builtin_amdgcn_s_barrier(); } while (0)
#define VMW(N) do { asm volatile("s_waitcnt vmcnt(" #N ")" ::: "memory"); \
                    __builtin_amdgcn_sched_barrier(0); } while (0)
#define SB0() __builtin_amdgcn_sched_barrier(0)

// ============ K0: bf16 weight images (swizzled LDS byte order) ========
__global__ __launch_bounds__(256, 2) void k_prep(
    const float* __restrict__ gc_w, const float* __restrict__ w_ih,
    const float* __restrict__ w_hh, ushort* __restrict__ ws)
{
  const int t = threadIdx.x;
  if (blockIdx.x < 24) {
    const int blk = blockIdx.x;
    const int kh = blk & 1, e = (blk >> 1) & 3, l = blk >> 3;
    const float* We = gc_w + (size_t)(l * NE + e) * H * H;
    ushort* dst = ws + (size_t)blk * IMG_GC_ELEMS;
    #pragma unroll
    for (int it = 0; it < 4; ++it) {
      int idx = t + it * 256;
      int r = idx >> 3, g = idx & 7;
      float v[8];
      #pragma unroll
      for (int j = 0; j < 8; ++j) v[j] = We[(kh * 64 + g * 8 + j) * H + r];
      *(short8*)&dst[gidx64(r, g)] = pack8f(v);
    }
  } else {
    const int blk = blockIdx.x - 24;
    const int c = blk & 7, m = blk >> 3;
    const float* Mat = m ? w_hh : w_ih;
    ushort* dst = ws + WIMG_SHORTS - IMG_GRU_BYTES / 2 + (size_t)blk * IMG_GRU_ELEMS;
    #pragma unroll
    for (int it = 0; it < 3; ++it) {
      int idx = t + it * 256;
      int rr = idx >> 4, g = idx & 15;
      int mrow = (rr >> 4) * H + 16 * c + (rr & 15);
      float v[8];
      #pragma unroll
      for (int j = 0; j < 8; ++j) v[j] = Mat[mrow * H + g * 8 + j];
      *(short8*)&dst[gidx128(rr, g)] = pack8f(v);
    }
  }
}

// ============ K1: input embedding -> bf16 h0 tails; adj->bf16 images ==========
template <bool ADJIMG>
__global__ __launch_bounds__(256, 2) void k_inemb(
    const float* __restrict__ x, const float* __restrict__ in_w,
    const float* __restrict__ in_b, const float* __restrict__ adj,
    ushort* __restrict__ ws, float* __restrict__ out)
{
  __shared__ float s_wt[FEAT * H];
  __shared__ float s_x[64 * FEAT];
  const int t = threadIdx.x;
  const int n = blockIdx.x >> 6, bt = blockIdx.x & 63, b0 = bt * 64;
  const float* wsrc = in_w + (size_t)n * FEAT * H;
  #pragma unroll
  for (int it = 0; it < 4; ++it) {
    int i4 = t + it * 256;
    *(f32x4*)&s_wt[i4 * 4] = *(const f32x4*)&wsrc[i4 * 4];
  }
  {
    int r = t >> 2, q = t & 3;
    const float* xs = x + ((size_t)(b0 + r) * NNODE + n) * FEAT;
    *(f32x4*)&s_x[r * 32 + q * 8]     = *(const f32x4*)&xs[q * 8];
    *(f32x4*)&s_x[r * 32 + q * 8 + 4] = *(const f32x4*)&xs[q * 8 + 4];
  }
  __syncthreads();
  const int h2 = t & 63, rp = t >> 6;
  const float bi0 = in_b[n * H + 2 * h2], bi1 = in_b[n * H + 2 * h2 + 1];
  #pragma unroll 1
  for (int m = 0; m < 16; ++m) {
    int r = rp + 4 * m;
    float a0 = bi0, a1 = bi1;
    #pragma unroll
    for (int d = 0; d < 32; ++d) {
      float xv = s_x[r * 32 + d];
      f32x2 wv = *(const f32x2*)&s_wt[d * H + 2 * h2];
      a0 += xv * wv.x; a1 += xv * wv.y;
    }
    unsigned p = cvtpk(a0, a1);
    ushort* tail = (ushort*)(out + ((size_t)(b0 + r) * NNODE + n) * H + 64);
    *(unsigned*)(tail + 2 * h2) = p;
  }
  if (ADJIMG) {
    const float* ab = adj + (size_t)blockIdx.x * NE * NNODE * NNODE;
    ushort* dst = ws + WIMG_SHORTS + (size_t)blockIdx.x * NE * ADJ_IMG_ELEMS;
    #pragma unroll 1
    for (int q = 0; q < 8; ++q) {
      int gi = t + q * 256;
      int e = gi >> 9, idx = gi & 511, r = idx >> 3, g = idx & 7;
      const float* src = ab + e * 4096 + r * 64 + g * 8;
      float v[8];
      #pragma unroll
      for (int j = 0; j < 8; ++j) v[j] = src[j];
      *(short8*)&dst[e * ADJ_IMG_ELEMS + gidx64(r, g)] = pack8f(v);
    }
  }
}

// ================= K2: RGCN+GRU, register-hidden + B-reuse tiling =============
template <bool ADJIMG>
__global__ __launch_bounds__(256, 2) void k_main(
    const float* __restrict__ adj,
    const float* __restrict__ gc_b,
    const float* __restrict__ b_ih, const float* __restrict__ b_hh,
    const ushort* __restrict__ wimg,
    float* __restrict__ out)
{
  __shared__ ushort s_u[128 * 64];      // S^T [h][j] / xf [i][h]  (16KB)
  __shared__ ushort s_stage[24576];     // 48KB union: edges{w0,w1,adj} / GRU{ih-pair,hh-pair}
  __shared__ float s_bias[1280];

  ushort* w0    = s_stage;              // 16KB
  ushort* w1    = s_stage + 8192;       // 16KB
  ushort* sadj  = s_stage + 16384;      // 8KB
  ushort* gru0  = s_stage;              // ih pair: [0,12288)
  ushort* gru1  = s_stage + 12288;      // hh pair: [12288,24576)

  const int t = threadIdx.x;
  const int b = blockIdx.x;
  const int w = t >> 6, lane = t & 63, lr = lane & 15, lq = lane >> 4;
  const int wm = w & 1, wn = w >> 1;    // M-half, N-half of this wave
  float* outb = out + (size_t)b * NNODE * H;
  const ushort* img_gru = wimg + WIMG_SHORTS - IMG_GRU_BYTES / 2;
  const ushort* aimg = wimg + WIMG_SHORTS + (size_t)b * NE * ADJ_IMG_ELEMS;

  // ---- prologue: W(l0,e0,kh0)->w0; hidden h0 -> registers; GRU biases ----
  STAGE(w0, wimg, 4);
  short8 cur[2][4];   // [row-tile][kstep]: rows 32*wm+16*rt+lr, k = 32*ks+8*lq..
  #pragma unroll
  for (int rt = 0; rt < 2; ++rt)
    #pragma unroll
    for (int ks = 0; ks < 4; ++ks) {
      int node = 32 * wm + 16 * rt + lr;
      cur[rt][ks] = *(const short8*)((const ushort*)(outb + (size_t)node * H + 64) + 32 * ks + 8 * lq);
    }
  #pragma unroll
  for (int it = 0; it < 3; ++it) {
    int idx = t + it * 256;
    s_bias[512 + idx] = (idx < 384) ? b_ih[idx] : b_hh[idx - 384];
  }
  __syncthreads();

  #pragma unroll 1
  for (int layer = 0; layer < NL; ++layer) {
    f32x4 agg[2][4];
    #pragma unroll
    for (int mt = 0; mt < 2; ++mt)
      #pragma unroll
      for (int nt = 0; nt < 4; ++nt) agg[mt][nt] = f32x4{0.f, 0.f, 0.f, 0.f};

    // ======== edges ====
    #pragma unroll 1
    for (int e = 0; e < NE; ++e) {
      const ushort* img_e = wimg + (size_t)((layer * NE + e) * 2) * IMG_GC_ELEMS;

      // ---- P2: stage W-kh1 + adj; mm1-kh0 (A from regs, B from w0) ----
      if (e == 0) {
        s_bias[t]       = gc_b[layer * 512 + t];
        s_bias[t + 256] = gc_b[layer * 512 + t + 256];
      }
      STAGE(w1, img_e + IMG_GC_ELEMS, 4);
      SB0();
      if (ADJIMG) {
        STAGE(sadj, aimg + (size_t)e * ADJ_IMG_ELEMS, 2);
        SB0();
      } else {
        const float* adj_e = adj + (((size_t)b * NE + e) * NNODE * NNODE);
        #pragma unroll
        for (int it = 0; it < 2; ++it) {
          int idx = t + it * 256;
          int i = idx >> 3, g = idx & 7;
          const float* src = adj_e + i * 64 + g * 8;
          float v[8];
          #pragma unroll
          for (int j = 0; j < 8; ++j) v[j] = src[j];
          *(short8*)&sadj[gidx64(i, g)] = pack8f(v);
        }
      }
      f32x4 Sacc[2][4];
      #pragma unroll
      for (int mt = 0; mt < 2; ++mt)
        #pragma unroll
        for (int nt = 0; nt < 4; ++nt) Sacc[mt][nt] = f32x4{0.f, 0.f, 0.f, 0.f};
      if (ADJIMG) VMW(6);               // w0 drained (6 just-issued may fly)
      __builtin_amdgcn_s_setprio(1);
      #pragma unroll
      for (int ks = 0; ks < 2; ++ks) {
        #pragma unroll
        for (int nt = 0; nt < 4; ++nt) {
          short8 bb = *(const short8*)&w0[gidx64(64 * wn + 16 * nt + lr, ks * 4 + lq)];
          #pragma unroll
          for (int mt = 0; mt < 2; ++mt)
            Sacc[mt][nt] = __builtin_amdgcn_mfma_f32_16x16x32_bf16(cur[mt][ks], bb, Sacc[mt][nt], 0, 0, 0);
        }
      }
      __builtin_amdgcn_s_setprio(0);
      if (ADJIMG) { VMW(2); BAR(); } else __syncthreads();

      // ---- P3: stage next (W-kh0' | GRU-ih0); mm1-kh1 (B from w1); pack S^T ----
      if (e < 3) { STAGE(w0, img_e + 2 * IMG_GC_ELEMS, 4); }
      else       { STAGE(gru0, img_gru, 3); }              // ih(0)
      SB0();
      __builtin_amdgcn_s_setprio(1);
      #pragma unroll
      for (int ks = 0; ks < 2; ++ks) {
        #pragma unroll
        for (int nt = 0; nt < 4; ++nt) {
          short8 bb = *(const short8*)&w1[gidx64(64 * wn + 16 * nt + lr, ks * 4 + lq)];
          #pragma unroll
          for (int mt = 0; mt < 2; ++mt)
            Sacc[mt][nt] = __builtin_amdgcn_mfma_f32_16x16x32_bf16(cur[mt][2 + ks], bb, Sacc[mt][nt], 0, 0, 0);
        }
      }
      __builtin_amdgcn_s_setprio(0);
      #pragma unroll
      for (int mt = 0; mt < 2; ++mt) {
        int j0 = 32 * wm + 16 * mt + 4 * lq;
        #pragma unroll
        for (int nt = 0; nt < 4; ++nt) {
          int h = 64 * wn + 16 * nt + lr;
          *(u64*)&s_u[gidx64(h, j0 >> 3) + (j0 & 7)] =
              pk4(Sacc[mt][nt][0], Sacc[mt][nt][1], Sacc[mt][nt][2], Sacc[mt][nt][3]);
        }
      }
      if (ADJIMG) { if (e < 3) { VMW(4); } else { VMW(3); } BAR(); } else __syncthreads();

      // ---- P4: [e3: stage GRU-ih1]; mm2 (A=s_adj, B=S^T); agg += relu ----
      if (e == 3) { STAGE(gru0 + 6144, img_gru + IMG_GRU_ELEMS, 3); SB0(); }
      {
        f32x4 Oacc[2][4];
        #pragma unroll
        for (int mt = 0; mt < 2; ++mt)
          #pragma unroll
          for (int nt = 0; nt < 4; ++nt) Oacc[mt][nt] = f32x4{0.f, 0.f, 0.f, 0.f};
        __builtin_amdgcn_s_setprio(1);
        #pragma unroll
        for (int ks = 0; ks < 2; ++ks) {
          short8 a[2];
          #pragma unroll
          for (int mt = 0; mt < 2; ++mt)
            a[mt] = *(const short8*)&sadj[gidx64(32 * wm + 16 * mt + lr, ks * 4 + lq)];
          #pragma unroll
          for (int nt = 0; nt < 4; ++nt) {
            short8 bb = *(const short8*)&s_u[gidx64(64 * wn + 16 * nt + lr, ks * 4 + lq)];
            #pragma unroll
            for (int mt = 0; mt < 2; ++mt)
              Oacc[mt][nt] = __builtin_amdgcn_mfma_f32_16x16x32_bf16(a[mt], bb, Oacc[mt][nt], 0, 0, 0);
          }
        }
        __builtin_amdgcn_s_setprio(0);
        #pragma unroll
        for (int mt = 0; mt < 2; ++mt)
          #pragma unroll
          for (int nt = 0; nt < 4; ++nt) {
            float bias = s_bias[e * 128 + 64 * wn + 16 * nt + lr];
            #pragma unroll
            for (int r = 0; r < 4; ++r)
              agg[mt][nt][r] += 0.25f * fmaxf(Oacc[mt][nt][r] + bias, 0.f);
          }
      }
      if (ADJIMG) { BAR(); } else __syncthreads();
    }  // edges

    // ---- xf = agg -> s_u row-major [i][h] ----
    #pragma unroll
    for (int mt = 0; mt < 2; ++mt)
      #pragma unroll
      for (int nt = 0; nt < 4; ++nt) {
        int h = 64 * wn + 16 * nt + lr;
        #pragma unroll
        for (int r = 0; r < 4; ++r)
          s_u[idx128(32 * wm + 16 * mt + 4 * lq + r, h)] = f2b(agg[mt][nt][r]);
      }
    __syncthreads();   // drains GRU-ih pair too

    // ======== GRU: 4 pair-steps; wave: chunk cc = 2p + wn, node-half wm ====
    #pragma unroll 1
    for (int p = 0; p < 4; ++p) {
      const int cc = 2 * p + wn;
      const ushort* ihb = gru0 + wn * 6144;
      const ushort* hhb = gru1 + wn * 6144;
      // stage hh pair; old-h loads (covered by gi)
      STAGE(gru1, img_gru + (size_t)(8 + 2 * p) * IMG_GRU_ELEMS, 3);
      STAGE(gru1 + 6144, img_gru + (size_t)(8 + 2 * p + 1) * IMG_GRU_ELEMS, 3);
      SB0();
      short4v holdv[2];
      #pragma unroll
      for (int nst = 0; nst < 2; ++nst) {
        int node = 16 * (2 * wm + nst) + lr;
        holdv[nst] = *(const short4v*)((const ushort*)(outb + (size_t)node * H + 64) + 16 * cc + 4 * lq);
      }
      f32x4 gi[3][2];
      #pragma unroll
      for (int tg = 0; tg < 3; ++tg)
        #pragma unroll
        for (int nst = 0; nst < 2; ++nst) gi[tg][nst] = f32x4{0.f, 0.f, 0.f, 0.f};
      __builtin_amdgcn_s_setprio(1);
      #pragma unroll
      for (int ks = 0; ks < 4; ++ks) {
        short8 bb[2];
        #pragma unroll
        for (int nst = 0; nst < 2; ++nst)
          bb[nst] = *(const short8*)&s_u[gidx128(16 * (2 * wm + nst) + lr, ks * 4 + lq)];
        #pragma unroll
        for (int tg = 0; tg < 3; ++tg) {
          short8 a = *(const short8*)&ihb[gidx128(16 * tg + lr, ks * 4 + lq)];
          #pragma unroll
          for (int nst = 0; nst < 2; ++nst)
            gi[tg][nst] = __builtin_amdgcn_mfma_f32_16x16x32_bf16(a, bb[nst], gi[tg][nst], 0, 0, 0);
        }
      }
      __builtin_amdgcn_s_setprio(0);
      __syncthreads();   // hh pair + old-h drained

      if (p < 3) {
        STAGE(gru0, img_gru + (size_t)(2 * (p + 1)) * IMG_GRU_ELEMS, 3);
        STAGE(gru0 + 6144, img_gru + (size_t)(2 * (p + 1) + 1) * IMG_GRU_ELEMS, 3);
      } else if (layer < 2) {
        STAGE(w0, wimg + (size_t)((layer + 1) * NE * 2) * IMG_GC_ELEMS, 4);
      }
      SB0();
      f32x4 gh[3][2];
      #pragma unroll
      for (int tg = 0; tg < 3; ++tg)
        #pragma unroll
        for (int nst = 0; nst < 2; ++nst) gh[tg][nst] = f32x4{0.f, 0.f, 0.f, 0.f};
      __builtin_amdgcn_s_setprio(1);
      #pragma unroll
      for (int ks = 0; ks < 4; ++ks) {
        #pragma unroll
        for (int tg = 0; tg < 3; ++tg) {
          short8 a = *(const short8*)&hhb[gidx128(16 * tg + lr, ks * 4 + lq)];
          #pragma unroll
          for (int nst = 0; nst < 2; ++nst)
            gh[tg][nst] = __builtin_amdgcn_mfma_f32_16x16x32_bf16(a, cur[nst][ks], gh[tg][nst], 0, 0, 0);
        }
      }
      __builtin_amdgcn_s_setprio(0);
      #pragma unroll
      for (int nst = 0; nst < 2; ++nst) {
        int node = 16 * (2 * wm + nst) + lr;
        float hf[4];
        #pragma unroll
        for (int r = 0; r < 4; ++r) {
          int mH = 16 * cc + 4 * lq + r;
          float rg = sigm(gi[0][nst][r] + s_bias[512 + mH] + gh[0][nst][r] + s_bias[896 + mH]);
          float zg = sigm(gi[1][nst][r] + s_bias[640 + mH] + gh[1][nst][r] + s_bias[1024 + mH]);
          float ng = tanh_(gi[2][nst][r] + s_bias[768 + mH] + rg * (gh[2][nst][r] + s_bias[1152 + mH]));
          float hold = b2f((ushort)holdv[nst][r]);
          hf[r] = (1.f - zg) * ng + zg * hold;
        }
        *(u64*)((ushort*)(outb + (size_t)node * H + 64) + 16 * cc + 4 * lq) =
            pk4(hf[0], hf[1], hf[2], hf[3]);
      }
      __syncthreads();   // h' writes drained; gh reads closed
    }  // pairs

    // ---- reload hidden regs from tails (block-private, L2-hot) ----
    if (layer < 2) {
      #pragma unroll
      for (int rt = 0; rt < 2; ++rt)
        #pragma unroll
        for (int ks = 0; ks < 4; ++ks) {
          int node = 32 * wm + 16 * rt + lr;
          cur[rt][ks] = *(const short8*)((const ushort*)(outb + (size_t)node * H + 64) + 32 * ks + 8 * lq);
        }
    }
  }  // layers
}

// ================= K3: output embedding + zero pad =============
__global__ __launch_bounds__(256, 2) void k_outemb(
    const float* __restrict__ out_w, const float* __restrict__ out_b,
    float* __restrict__ out)
{
  __shared__ float s_wt[H * FEAT];
  __shared__ float s_c[64 * 132];
  const int t = threadIdx.x;
  const int n = blockIdx.x >> 6, bt = blockIdx.x & 63, b0 = bt * 64;
  const float* wsrc = out_w + (size_t)n * H * FEAT;
  #pragma unroll
  for (int it = 0; it < 4; ++it) {
    int i4 = t + it * 256;
    *(f32x4*)&s_wt[i4 * 4] = *(const f32x4*)&wsrc[i4 * 4];
  }
  #pragma unroll
  for (int it = 0; it < 4; ++it) {
    int idx = t + it * 256;
    int r = idx >> 4, g = idx & 15;
    const ushort* tail = (const ushort*)(out + ((size_t)(b0 + r) * NNODE + n) * H + 64);
    short8 v = *(const short8*)(tail + g * 8);
    #pragma unroll
    for (int j = 0; j < 8; ++j) s_c[r * 132 + g * 8 + j] = b2f((ushort)v[j]);
  }
  __syncthreads();
  const int d = t & 31, rq = t >> 5;
  const float bias = out_b[n * FEAT + d];
  float accs[8];
  #pragma unroll
  for (int m = 0; m < 8; ++m) {
    int r = rq + 8 * m;
    float a = bias;
    #pragma unroll 8
    for (int k = 0; k < H; ++k) a += s_c[r * 132 + k] * s_wt[k * FEAT + d];
    accs[m] = a;
  }
  #pragma unroll
  for (int m = 0; m < 8; ++m) {
    int r = rq + 8 * m;
    out[((size_t)(b0 + r) * NNODE + n) * H + d] = accs[m];
  }
  #pragma unroll
  for (int q = 0; q < 6; ++q) {
    int idx = t + q * 256;
    int r = idx / 24, c4 = idx - r * 24;
    *(f32x4*)&out[((size_t)(b0 + r) * NNODE + n) * H + FEAT + c4 * 4] =
        f32x4{0.f, 0.f, 0.f, 0.f};
  }
}

extern "C" void kernel_launch(void* const* d_in, const int* in_sizes, int n_in,
                              void* d_out, int out_size, void* d_ws, size_t ws_size,
                              hipStream_t stream) {
  const float* x     = (const float*)d_in[0];
  const float* adj   = (const float*)d_in[1];
  const float* in_w  = (const float*)d_in[2];
  const float* in_b  = (const float*)d_in[3];
  const float* out_w = (const float*)d_in[4];
  const float* out_b = (const float*)d_in[5];
  const float* gc_w  = (const float*)d_in[6];
  const float* gc_b  = (const float*)d_in[7];
  const float* w_ih  = (const float*)d_in[8];
  const float* w_hh  = (const float*)d_in[9];
  const float* b_ih  = (const float*)d_in[10];
  const float* b_hh  = (const float*)d_in[11];
  (void)in_sizes; (void)n_in; (void)out_size;
  ushort* wimg = (ushort*)d_ws;
  const bool full = ws_size >= WS_FULL;
  hipLaunchKernelGGL(k_prep, dim3(40), dim3(256), 0, stream, gc_w, w_ih, w_hh, wimg);
  if (full) {
    hipLaunchKernelGGL(k_inemb<true>, dim3(NBATCH), dim3(256), 0, stream,
                       x, in_w, in_b, adj, wimg, (float*)d_out);
    hipLaunchKernelGGL(k_main<true>, dim3(NBATCH), dim3(256), 0, stream,
                       adj, gc_b, b_ih, b_hh, wimg, (float*)d_out);
  } else {
    hipLaunchKernelGGL(k_inemb<false>, dim3(NBATCH), dim3(256), 0, stream,
                       x, in_w, in_b, adj, wimg, (float*)d_out);
    hipLaunchKernelGGL(k_main<false>, dim3(NBATCH), dim3(256), 0, stream,
                       adj, gc_b, b_ih, b_hh, wimg, (float*)d_out);
  }
  hipLaunchKernelGGL(k_outemb, dim3(NBATCH), dim3(256), 0, stream, out_w, out_b, (float*)d_out);
}